// Round 2
// baseline (1131.742 us; speedup 1.0000x reference)
//
#include <hip/hip_runtime.h>
#include <math.h>

// Problem constants (fixed by reference)
#define NN 8000
#define KK 8
#define EE (NN*KK)        // 64000 edges
#define TT (EE*KK)        // 512000 triplets
#define CC 32
#define SS 9
#define FF 128
#define BB 128
#define CO 64
#define NPAIR 36          // unique (a<=b) pairs of 8 slots
#define NTASK (NN*NPAIR)  // 288000 unique a2-MLP evals

// Gaussian expansion: centers k*6/127, width = 3/128 -> 1/(2w^2) = 8192/9
#define GSTEP (6.0f/127.0f)
#define GINV  (8192.0f/9.0f)

__device__ __forceinline__ float b2f(unsigned short u) {
    return __uint_as_float(((unsigned int)u) << 16);
}
__device__ __forceinline__ unsigned short f2b(float f) {
    unsigned int x = __float_as_uint(f);
    return (unsigned short)((x + 0x7FFFu + ((x >> 16) & 1u)) >> 16);
}
template<bool BF> __device__ __forceinline__ float LD(const void* p, size_t i) {
    if constexpr (BF) return b2f(((const unsigned short*)p)[i]);
    else              return ((const float*)p)[i];
}

// ---------------------------------------------------------------------------
// dtype probe: edge_sh ~ N(0,1). Reading bf16-packed data as fp32 puts bf16
// exponent+mantissa bits into the fp32 exponent field -> |x| ~ 2^+-125, Inf,
// or NaN for every element. fp32 data -> all values sane. flag: 1 = bf16.
__global__ void k_detect(const void* esh, int* flag) {
    int lane = threadIdx.x;  // 64 threads
    const float* p = (const float*)esh;
    int sane = 0;
    #pragma unroll
    for (int i = 0; i < 8; ++i) {
        float ax = fabsf(p[lane * 8 + i]);
        if (ax > 1e-20f && ax < 1e20f) sane++;   // NaN/Inf fail both
    }
    #pragma unroll
    for (int m = 1; m < 64; m <<= 1) sane += __shfl_xor(sane, m, 64);
    if (lane == 0) *flag = (sane > 256) ? 0 : 1;
}

// ---------------------------------------------------------------------------
// Kernel 1: value[e,f] = (sum_cs ein[e,c]*esh[e,s]*Wtp[cs,f]) * (elem[e,:] @ Wrad[:,f])
// block = 128 threads (one per f), 16 edges per block. Output stored bf16.
template<bool BF> __device__ __forceinline__ void value_body(
    const void* ein, const void* esh, const void* elem,
    const void* wtp, const void* wrad, unsigned short* value,
    float* A, float* EL)
{
    const int e0 = blockIdx.x * 16;
    const int tid = threadIdx.x;
    for (int idx = tid; idx < 288*16; idx += 128) {
        int cs = idx >> 4, ei = idx & 15;
        int c = cs / 9, s = cs - c * 9;
        A[idx] = LD<BF>(ein, (size_t)(e0+ei)*CC + c) * LD<BF>(esh, (size_t)(e0+ei)*SS + s);
    }
    for (int ei = 0; ei < 16; ++ei)
        EL[tid*17 + ei] = LD<BF>(elem, (size_t)(e0+ei)*BB + tid);
    __syncthreads();
    float acc[16], rac[16];
    #pragma unroll
    for (int i = 0; i < 16; ++i) { acc[i] = 0.f; rac[i] = 0.f; }
    for (int cs = 0; cs < 288; ++cs) {
        float w = LD<BF>(wtp, (size_t)cs*FF + tid);
        const float4* ap = (const float4*)(&A[cs*16]);
        #pragma unroll
        for (int q = 0; q < 4; ++q) {
            float4 a4 = ap[q];
            acc[q*4+0] += a4.x * w; acc[q*4+1] += a4.y * w;
            acc[q*4+2] += a4.z * w; acc[q*4+3] += a4.w * w;
        }
    }
    for (int k = 0; k < 128; ++k) {
        float w = LD<BF>(wrad, (size_t)k*FF + tid);
        #pragma unroll
        for (int ei = 0; ei < 16; ++ei) rac[ei] += EL[k*17 + ei] * w;
    }
    #pragma unroll
    for (int ei = 0; ei < 16; ++ei)
        value[(size_t)(e0+ei)*FF + tid] = f2b(acc[ei] * rac[ei]);
}

__global__ __launch_bounds__(128) void k_value(
    const int* __restrict__ flag, const void* ein, const void* esh, const void* elem,
    const void* wtp, const void* wrad, unsigned short* __restrict__ value)
{
    __shared__ float A[288*16];
    __shared__ float EL[128*17];
    if (*flag) value_body<true >(ein, esh, elem, wtp, wrad, value, A, EL);
    else       value_body<false>(ein, esh, elem, wtp, wrad, value, A, EL);
}

// ---------------------------------------------------------------------------
// Shared MLP helpers (Linear->LN->SiLU->Linear->LN->SiLU->Linear), wave-level.
template<bool BF> __device__ __forceinline__ void load_weights(
    int tid, int widx,
    const void* wain, const void* bain, const void* ga1p, const void* bea1p,
    const void* wam,  const void* bam,  const void* ga2p, const void* bea2p,
    const void* wao,  const void* bao,
    float* sW1, float* sW2, float* sW3t,
    float* sb1, float* sg1, float* sbe1, float* sb2, float* sg2, float* sbe2, float* sb3)
{
    for (int i = tid; i < 8192; i += 256) sW1[i] = LD<BF>(wain, (size_t)widx*8192 + i);
    for (int i = tid; i < 4096; i += 256) sW2[i] = LD<BF>(wam,  (size_t)widx*4096 + i);
    { int i = tid; if (i < 256) sW3t[(i & 3)*64 + (i >> 2)] = LD<BF>(wao, (size_t)widx*256 + i); }
    if (tid < 64) {
        sb1[tid]  = LD<BF>(bain, (size_t)widx*64 + tid);
        sg1[tid]  = LD<BF>(ga1p, (size_t)widx*64 + tid);
        sbe1[tid] = LD<BF>(bea1p,(size_t)widx*64 + tid);
        sb2[tid]  = LD<BF>(bam,  (size_t)widx*64 + tid);
        sg2[tid]  = LD<BF>(ga2p, (size_t)widx*64 + tid);
        sbe2[tid] = LD<BF>(bea2p,(size_t)widx*64 + tid);
    }
    if (tid < 4) sb3[tid] = LD<BF>(bao, (size_t)widx*4 + tid);
}

// One wave evaluates one MLP; input = gaussian expansion of scalar d.
// Contains 2 block-uniform __syncthreads -> called uniformly by all waves.
__device__ __forceinline__ float4 mlp_wave(
    float d, int lane,
    const float* __restrict__ sW1, const float* __restrict__ sW2, const float* __restrict__ sW3t,
    const float* __restrict__ sb1, const float* __restrict__ sg1, const float* __restrict__ sbe1,
    const float* __restrict__ sb2, const float* __restrict__ sg2, const float* __restrict__ sbe2,
    const float* __restrict__ sb3, float* __restrict__ xs, float* __restrict__ hs)
{
    float c0 = lane * GSTEP, c1 = (lane + 64) * GSTEP;
    float d0 = d - c0, d1 = d - c1;
    xs[lane]      = __expf(-(d0*d0) * GINV);
    xs[lane + 64] = __expf(-(d1*d1) * GINV);
    __syncthreads();   // (A)
    float acc = sb1[lane];
    #pragma unroll
    for (int k = 0; k < 128; k += 4) {
        float4 x4 = *(const float4*)(&xs[k]);
        acc += x4.x * sW1[(k+0)*64 + lane];
        acc += x4.y * sW1[(k+1)*64 + lane];
        acc += x4.z * sW1[(k+2)*64 + lane];
        acc += x4.w * sW1[(k+3)*64 + lane];
    }
    float s = acc;
    #pragma unroll
    for (int m = 1; m < 64; m <<= 1) s += __shfl_xor(s, m, 64);
    float mu = s * (1.0f/64.0f);
    float dv = acc - mu;
    float q = dv * dv;
    #pragma unroll
    for (int m = 1; m < 64; m <<= 1) q += __shfl_xor(q, m, 64);
    float h = dv * rsqrtf(q * (1.0f/64.0f) + 1e-6f) * sg1[lane] + sbe1[lane];
    h = h * (1.0f / (1.0f + __expf(-h)));      // SiLU
    hs[lane] = h;
    __syncthreads();   // (B)
    float acc2 = sb2[lane];
    #pragma unroll
    for (int k = 0; k < 64; k += 4) {
        float4 h4 = *(const float4*)(&hs[k]);
        acc2 += h4.x * sW2[(k+0)*64 + lane];
        acc2 += h4.y * sW2[(k+1)*64 + lane];
        acc2 += h4.z * sW2[(k+2)*64 + lane];
        acc2 += h4.w * sW2[(k+3)*64 + lane];
    }
    float s2 = acc2;
    #pragma unroll
    for (int m = 1; m < 64; m <<= 1) s2 += __shfl_xor(s2, m, 64);
    float mu2 = s2 * (1.0f/64.0f);
    float dv2 = acc2 - mu2;
    float q2 = dv2 * dv2;
    #pragma unroll
    for (int m = 1; m < 64; m <<= 1) q2 += __shfl_xor(q2, m, 64);
    float h2 = dv2 * rsqrtf(q2 * (1.0f/64.0f) + 1e-6f) * sg2[lane] + sbe2[lane];
    h2 = h2 * (1.0f / (1.0f + __expf(-h2)));
    float p0 = h2 * sW3t[0*64 + lane];
    float p1 = h2 * sW3t[1*64 + lane];
    float p2 = h2 * sW3t[2*64 + lane];
    float p3 = h2 * sW3t[3*64 + lane];
    #pragma unroll
    for (int m = 1; m < 64; m <<= 1) {
        p0 += __shfl_xor(p0, m, 64);
        p1 += __shfl_xor(p1, m, 64);
        p2 += __shfl_xor(p2, m, 64);
        p3 += __shfl_xor(p3, m, 64);
    }
    float4 o;
    o.x = p0 + sb3[0]; o.y = p1 + sb3[1]; o.z = p2 + sb3[2]; o.w = p3 + sb3[3];
    return o;
}

// ---------------------------------------------------------------------------
// Kernel 2: a1[e,0..3] = MLP0(gexp(|edge_vec[e]|)) — wave per edge.
template<bool BF> __device__ __forceinline__ void alpha1_body(
    const void* evec,
    const void* wain, const void* bain, const void* ga1p, const void* bea1p,
    const void* wam,  const void* bam,  const void* ga2p, const void* bea2p,
    const void* wao,  const void* bao, float* a1buf,
    float* sW1, float* sW2, float* sW3t,
    float* sb1, float* sg1, float* sbe1, float* sb2, float* sg2, float* sbe2, float* sb3,
    float* xsb, float* hsb)
{
    const int tid = threadIdx.x;
    load_weights<BF>(tid, 0, wain, bain, ga1p, bea1p, wam, bam, ga2p, bea2p, wao, bao,
                     sW1, sW2, sW3t, sb1, sg1, sbe1, sb2, sg2, sbe2, sb3);
    __syncthreads();
    const int lane = tid & 63, ws = tid >> 6;
    float* xs = xsb + ws * 128;
    float* hs = hsb + ws * 64;
    for (int base = blockIdx.x * 4; base < EE; base += gridDim.x * 4) {
        int e = base + ws;
        float vx = LD<BF>(evec, (size_t)e*3+0);
        float vy = LD<BF>(evec, (size_t)e*3+1);
        float vz = LD<BF>(evec, (size_t)e*3+2);
        float d = sqrtf(vx*vx + vy*vy + vz*vz);
        float4 o = mlp_wave(d, lane, sW1, sW2, sW3t, sb1, sg1, sbe1, sb2, sg2, sbe2, sb3, xs, hs);
        if (lane == 0) *(float4*)(&a1buf[(size_t)e*4]) = o;
    }
}

__global__ __launch_bounds__(256) void k_alpha1(
    const int* __restrict__ flag, const void* evec,
    const void* wain, const void* bain, const void* ga1p, const void* bea1p,
    const void* wam,  const void* bam,  const void* ga2p, const void* bea2p,
    const void* wao,  const void* bao, float* __restrict__ a1buf)
{
    __shared__ float sW1[128*64], sW2[64*64], sW3t[4*64];
    __shared__ float sb1[64], sg1[64], sbe1[64], sb2[64], sg2[64], sbe2[64], sb3[4];
    __shared__ float xsb[4*128], hsb[4*64];
    if (*flag) alpha1_body<true >(evec, wain, bain, ga1p, bea1p, wam, bam, ga2p, bea2p, wao, bao,
                                  a1buf, sW1, sW2, sW3t, sb1, sg1, sbe1, sb2, sg2, sbe2, sb3, xsb, hsb);
    else       alpha1_body<false>(evec, wain, bain, ga1p, bea1p, wam, bam, ga2p, bea2p, wao, bao,
                                  a1buf, sW1, sW2, sW3t, sb1, sg1, sbe1, sb2, sg2, sbe2, sb3, xsb, hsb);
}

// Unique unordered pair tables (a<=b), 36 entries.
__device__ const int UA[NPAIR] = {0,0,0,0,0,0,0,0,1,1,1,1,1,1,1,2,2,2,2,2,2,3,3,3,3,3,4,4,4,4,5,5,5,6,6,7};
__device__ const int UB[NPAIR] = {0,1,2,3,4,5,6,7,1,2,3,4,5,6,7,2,3,4,5,6,7,3,4,5,6,7,4,5,6,7,5,6,7,6,7,7};

// Kernel 3: per node i, pair (a<=b): a2 = MLP1(gexp(|vec[ib]-vec[ia]|)) (symmetric);
// alpha[t] = a1[src]*a2 for triplets (i,a,b) and (i,b,a).
template<bool BF> __device__ __forceinline__ void alpha2_body(
    const void* evec,
    const void* wain, const void* bain, const void* ga1p, const void* bea1p,
    const void* wam,  const void* bam,  const void* ga2p, const void* bea2p,
    const void* wao,  const void* bao, const float* a1buf, float* alpha,
    float* sW1, float* sW2, float* sW3t,
    float* sb1, float* sg1, float* sbe1, float* sb2, float* sg2, float* sbe2, float* sb3,
    float* xsb, float* hsb)
{
    const int tid = threadIdx.x;
    load_weights<BF>(tid, 1, wain, bain, ga1p, bea1p, wam, bam, ga2p, bea2p, wao, bao,
                     sW1, sW2, sW3t, sb1, sg1, sbe1, sb2, sg2, sbe2, sb3);
    __syncthreads();
    const int lane = tid & 63, ws = tid >> 6;
    float* xs = xsb + ws * 128;
    float* hs = hsb + ws * 64;
    for (int base = blockIdx.x * 4; base < NTASK; base += gridDim.x * 4) {
        int task = base + ws;
        int i = task / NPAIR;
        int u = task - i * NPAIR;
        int a = UA[u], b = UB[u];
        int ea = i * 8 + a, eb = i * 8 + b;
        float ax = LD<BF>(evec,(size_t)ea*3+0), ay = LD<BF>(evec,(size_t)ea*3+1), az = LD<BF>(evec,(size_t)ea*3+2);
        float bx = LD<BF>(evec,(size_t)eb*3+0), by = LD<BF>(evec,(size_t)eb*3+1), bz = LD<BF>(evec,(size_t)eb*3+2);
        float dx = bx - ax, dy = by - ay, dz = bz - az;
        float d = sqrtf(dx*dx + dy*dy + dz*dz);
        float4 o = mlp_wave(d, lane, sW1, sW2, sW3t, sb1, sg1, sbe1, sb2, sg2, sbe2, sb3, xs, hs);
        if (lane == 0) {
            float4 g = *(const float4*)(&a1buf[(size_t)eb*4]);   // src = eb
            float4 r; r.x = o.x*g.x; r.y = o.y*g.y; r.z = o.z*g.z; r.w = o.w*g.w;
            *(float4*)(&alpha[(size_t)(ea*8 + b)*4]) = r;
        }
        if (lane == 1 && a != b) {
            float4 g = *(const float4*)(&a1buf[(size_t)ea*4]);   // src = ea
            float4 r; r.x = o.x*g.x; r.y = o.y*g.y; r.z = o.z*g.z; r.w = o.w*g.w;
            *(float4*)(&alpha[(size_t)(eb*8 + a)*4]) = r;
        }
    }
}

__global__ __launch_bounds__(256) void k_alpha2(
    const int* __restrict__ flag, const void* evec,
    const void* wain, const void* bain, const void* ga1p, const void* bea1p,
    const void* wam,  const void* bam,  const void* ga2p, const void* bea2p,
    const void* wao,  const void* bao,
    const float* __restrict__ a1buf, float* __restrict__ alpha)
{
    __shared__ float sW1[128*64], sW2[64*64], sW3t[4*64];
    __shared__ float sb1[64], sg1[64], sbe1[64], sb2[64], sg2[64], sbe2[64], sb3[4];
    __shared__ float xsb[4*128], hsb[4*64];
    if (*flag) alpha2_body<true >(evec, wain, bain, ga1p, bea1p, wam, bam, ga2p, bea2p, wao, bao,
                                  a1buf, alpha, sW1, sW2, sW3t, sb1, sg1, sbe1, sb2, sg2, sbe2, sb3, xsb, hsb);
    else       alpha2_body<false>(evec, wain, bain, ga1p, bea1p, wam, bam, ga2p, bea2p, wao, bao,
                                  a1buf, alpha, sW1, sW2, sW3t, sb1, sg1, sbe1, sb2, sg2, sbe2, sb3, xsb, hsb);
}

// ---------------------------------------------------------------------------
// Kernel 4: per target edge e: softmax over its 8 triplets (per head), aggregate
// value rows, apply W_lin -> eout[e,0..63] (stored bf16). Wave per edge.
template<bool BF> __device__ __forceinline__ void edge_body(
    const float* alpha, const unsigned short* value,
    const int* src_eid, const int* inv_index,
    const void* wlin, unsigned short* eout,
    float* WL, float* alsb, float* feab)
{
    const int tid = threadIdx.x;
    for (int i = tid; i < 8192; i += 256) WL[i] = LD<BF>(wlin, (size_t)i);
    __syncthreads();
    const int lane = tid & 63, ws = tid >> 6;
    float* als = alsb + ws * 32;
    float* fea = feab + ws * 128;
    for (int base = blockIdx.x * 4; base < EE; base += gridDim.x * 4) {
        int e = base + ws;
        float v = -1e30f;
        if (lane < 32) v = alpha[(size_t)e*32 + lane];   // lane = b*4+h
        float vm = v;
        vm = fmaxf(vm, __shfl_xor(vm, 4, 64));
        vm = fmaxf(vm, __shfl_xor(vm, 8, 64));
        vm = fmaxf(vm, __shfl_xor(vm, 16, 64));
        float ex = __expf(v - vm);
        float den = ex;
        den += __shfl_xor(den, 4, 64);
        den += __shfl_xor(den, 8, 64);
        den += __shfl_xor(den, 16, 64);
        float al = ex / (den + 1e-16f);
        if (lane < 32) als[lane] = al;
        __syncthreads();
        float f0 = 0.f, f1 = 0.f;
        int h0 = lane >> 5;
        #pragma unroll
        for (int bq = 0; bq < 8; ++bq) {
            int se = src_eid[e*8 + bq];
            int row = inv_index[se];
            const unsigned short* vr = &value[(size_t)row * FF];
            f0 += als[bq*4 + h0]     * b2f(vr[lane]);
            f1 += als[bq*4 + h0 + 2] * b2f(vr[64 + lane]);
        }
        fea[lane] = f0; fea[64 + lane] = f1;
        __syncthreads();
        float acc = 0.f;
        #pragma unroll
        for (int f = 0; f < 128; f += 4) {
            float4 fe = *(const float4*)(&fea[f]);
            acc += fe.x * WL[(f+0)*64 + lane];
            acc += fe.y * WL[(f+1)*64 + lane];
            acc += fe.z * WL[(f+2)*64 + lane];
            acc += fe.w * WL[(f+3)*64 + lane];
        }
        eout[(size_t)e*64 + lane] = f2b(acc);
    }
}

__global__ __launch_bounds__(256) void k_edge(
    const int* __restrict__ flag,
    const float* __restrict__ alpha, const unsigned short* __restrict__ value,
    const int* __restrict__ src_eid, const int* __restrict__ inv_index,
    const void* wlin, unsigned short* __restrict__ eout)
{
    __shared__ float WL[128*64];
    __shared__ float alsb[4*32];
    __shared__ float feab[4*128];
    if (*flag) edge_body<true >(alpha, value, src_eid, inv_index, wlin, eout, WL, alsb, feab);
    else       edge_body<false>(alpha, value, src_eid, inv_index, wlin, eout, WL, alsb, feab);
}

// ---------------------------------------------------------------------------
// Kernel 5: node_out[n,o] = sum_s eout[inv_index[n*8+s], o]; output dtype per flag.
__global__ __launch_bounds__(256) void k_node(
    const int* __restrict__ flag, const unsigned short* __restrict__ eout,
    const int* __restrict__ inv_index, void* __restrict__ out)
{
    int gid = blockIdx.x * 256 + threadIdx.x;   // exactly N*64 = 512000
    int n = gid >> 6, o = gid & 63;
    float s = 0.f;
    #pragma unroll
    for (int q = 0; q < 8; ++q) {
        int row = inv_index[n*8 + q];
        s += b2f(eout[(size_t)row*64 + o]);
    }
    if (*flag) ((unsigned short*)out)[gid] = f2b(s);
    else       ((float*)out)[gid] = s;
}

// ---------------------------------------------------------------------------
extern "C" void kernel_launch(void* const* d_in, const int* in_sizes, int n_in,
                              void* d_out, int out_size, void* d_ws, size_t ws_size,
                              hipStream_t stream)
{
    const void* ein  = d_in[0];   // edge_in [E,32]
    const void* esh  = d_in[1];   // edge_sh [E,9]
    const void* elem = d_in[2];   // edge_length_embedding [E,128]
    const void* evec = d_in[3];   // edge_vec [E,3]
    const void* wtp  = d_in[4];   // W_tp2 [32,9,128]
    const void* wrad = d_in[5];   // W_rad [128,128]
    const void* wlin = d_in[6];   // W_lin [128,64]
    const void* wain = d_in[7];   // Wa_in [2,128,64]
    const void* bain = d_in[8];
    const void* ga1p = d_in[9];
    const void* bea1p= d_in[10];
    const void* wam  = d_in[11];  // Wa_mid [2,64,64]
    const void* bam  = d_in[12];
    const void* ga2p = d_in[13];
    const void* bea2p= d_in[14];
    const void* wao  = d_in[15];  // Wa_out [2,64,4]
    const void* bao  = d_in[16];
    const int* inv_index = (const int*)d_in[17];
    const int* src_eid   = (const int*)d_in[19];

    // workspace layout (33.8 MB total), all offsets 16B-aligned
    char* ws = (char*)d_ws;
    int*            flag  = (int*)ws;                               // 16 B
    unsigned short* value = (unsigned short*)(ws + 16);             // E*128*2 = 16,384,000
    float*          a1buf = (float*)(ws + 16 + 16384000);           // E*4*4   =  1,024,000
    float*          alpha = (float*)(ws + 16 + 16384000 + 1024000); // T*4*4   =  8,192,000
    unsigned short* eoutb = (unsigned short*)(ws + 16 + 16384000 + 1024000 + 8192000); // E*64*2 = 8,192,000

    hipLaunchKernelGGL(k_detect, dim3(1), dim3(64), 0, stream, esh, flag);
    hipLaunchKernelGGL(k_value,  dim3(EE/16), dim3(128), 0, stream,
                       flag, ein, esh, elem, wtp, wrad, value);
    hipLaunchKernelGGL(k_alpha1, dim3(512),  dim3(256), 0, stream,
                       flag, evec, wain, bain, ga1p, bea1p, wam, bam, ga2p, bea2p, wao, bao, a1buf);
    hipLaunchKernelGGL(k_alpha2, dim3(1024), dim3(256), 0, stream,
                       flag, evec, wain, bain, ga1p, bea1p, wam, bam, ga2p, bea2p, wao, bao,
                       a1buf, alpha);
    hipLaunchKernelGGL(k_edge,   dim3(1024), dim3(256), 0, stream,
                       flag, alpha, value, src_eid, inv_index, wlin, eoutb);
    hipLaunchKernelGGL(k_node,   dim3((NN*CO)/256), dim3(256), 0, stream,
                       flag, eoutb, inv_index, d_out);
}

// Round 3
// 459.388 us; speedup vs baseline: 2.4636x; 2.4636x over previous
//
#include <hip/hip_runtime.h>
#include <math.h>

// Problem constants (fixed by reference)
#define NN 8000
#define KK 8
#define EE (NN*KK)        // 64000 edges
#define TT (EE*KK)        // 512000 triplets
#define CC 32
#define SS 9
#define FF 128
#define BB 128
#define CO 64
#define NPAIR 36          // unique (a<=b) pairs of 8 slots
#define NTASK (NN*NPAIR)  // 288000 unique a2-MLP evals
#define NB1 (EE/16)       // 4000 batches of 16 edges
#define NB2 (NTASK/16)    // 18000 batches of 16 pair-tasks

// Gaussian expansion: centers k*6/127, width = 3/128 -> 1/(2w^2) = 8192/9
#define GSTEP (6.0f/127.0f)
#define GINV  (8192.0f/9.0f)

typedef __attribute__((ext_vector_type(8))) short short8;
typedef __attribute__((ext_vector_type(4))) float acc4;

__device__ __forceinline__ float b2f(unsigned short u) {
    return __uint_as_float(((unsigned int)u) << 16);
}
__device__ __forceinline__ unsigned short f2b(float f) {
    unsigned int x = __float_as_uint(f);
    return (unsigned short)((x + 0x7FFFu + ((x >> 16) & 1u)) >> 16);
}
template<bool BF> __device__ __forceinline__ float LD(const void* p, size_t i) {
    if constexpr (BF) return b2f(((const unsigned short*)p)[i]);
    else              return ((const float*)p)[i];
}
template<bool BF> __device__ __forceinline__ unsigned short LDB(const void* p, size_t i) {
    if constexpr (BF) return ((const unsigned short*)p)[i];       // already bf16: exact
    else              return f2b(((const float*)p)[i]);
}

// ---------------------------------------------------------------------------
// dtype probe: flag=1 means inputs are bf16.
__global__ void k_detect(const void* esh, int* flag) {
    int lane = threadIdx.x;  // 64 threads
    const float* p = (const float*)esh;
    int sane = 0;
    #pragma unroll
    for (int i = 0; i < 8; ++i) {
        float ax = fabsf(p[lane * 8 + i]);
        if (ax > 1e-20f && ax < 1e20f) sane++;   // NaN/Inf fail both
    }
    #pragma unroll
    for (int m = 1; m < 64; m <<= 1) sane += __shfl_xor(sane, m, 64);
    if (lane == 0) *flag = (sane > 256) ? 0 : 1;
}

// ---------------------------------------------------------------------------
// Kernel 1: value[e,f] = (sum_cs ein[e,c]*esh[e,s]*Wtp[cs,f]) * (elem[e,:] @ Wrad[:,f])
template<bool BF> __device__ __forceinline__ void value_body(
    const void* ein, const void* esh, const void* elem,
    const void* wtp, const void* wrad, unsigned short* value,
    float* A, float* EL)
{
    const int e0 = blockIdx.x * 16;
    const int tid = threadIdx.x;
    for (int idx = tid; idx < 288*16; idx += 128) {
        int cs = idx >> 4, ei = idx & 15;
        int c = cs / 9, s = cs - c * 9;
        A[idx] = LD<BF>(ein, (size_t)(e0+ei)*CC + c) * LD<BF>(esh, (size_t)(e0+ei)*SS + s);
    }
    for (int ei = 0; ei < 16; ++ei)
        EL[tid*17 + ei] = LD<BF>(elem, (size_t)(e0+ei)*BB + tid);
    __syncthreads();
    float acc[16], rac[16];
    #pragma unroll
    for (int i = 0; i < 16; ++i) { acc[i] = 0.f; rac[i] = 0.f; }
    for (int cs = 0; cs < 288; ++cs) {
        float w = LD<BF>(wtp, (size_t)cs*FF + tid);
        const float4* ap = (const float4*)(&A[cs*16]);
        #pragma unroll
        for (int q = 0; q < 4; ++q) {
            float4 a4 = ap[q];
            acc[q*4+0] += a4.x * w; acc[q*4+1] += a4.y * w;
            acc[q*4+2] += a4.z * w; acc[q*4+3] += a4.w * w;
        }
    }
    for (int k = 0; k < 128; ++k) {
        float w = LD<BF>(wrad, (size_t)k*FF + tid);
        #pragma unroll
        for (int ei = 0; ei < 16; ++ei) rac[ei] += EL[k*17 + ei] * w;
    }
    #pragma unroll
    for (int ei = 0; ei < 16; ++ei)
        value[(size_t)(e0+ei)*FF + tid] = f2b(acc[ei] * rac[ei]);
}

__global__ __launch_bounds__(128) void k_value(
    const int* __restrict__ flag, const void* ein, const void* esh, const void* elem,
    const void* wtp, const void* wrad, unsigned short* __restrict__ value)
{
    __shared__ float A[288*16];
    __shared__ float EL[128*17];
    if (*flag) value_body<true >(ein, esh, elem, wtp, wrad, value, A, EL);
    else       value_body<false>(ein, esh, elem, wtp, wrad, value, A, EL);
}

// ---------------------------------------------------------------------------
// MFMA-batched MLP: 16 tasks per wave.
//   layer1: D1[16 tasks][64 hid] = X[16][128] @ W1[128][64]   (16 MFMAs 16x16x32)
//   layer2: D2[16][64] = H1[16][64] @ W2[64][64]              (8 MFMAs)
//   layer3: 64->4 via VALU + shuffle reduce
// Weights live in VGPR fragments for the whole kernel (zero LDS weight traffic).
// X is the gaussian expansion of wave-held d[16], computed directly in A-frag
// layout (A[m=lane&15][k=(lane>>4)*8+j]).  C/D layout: col=lane&15 (= hidden n
// within tile), row=(lane>>4)*4+reg (= task m).  LDS round-trip (per-wave 2KB
// slice, XOR-swizzled) converts C-layout H to A-layout for the next MFMA.

__device__ const int UA[NPAIR] = {0,0,0,0,0,0,0,0,1,1,1,1,1,1,1,2,2,2,2,2,2,3,3,3,3,3,4,4,4,4,5,5,5,6,6,7};
__device__ const int UB[NPAIR] = {0,1,2,3,4,5,6,7,1,2,3,4,5,6,7,2,3,4,5,6,7,3,4,5,6,7,4,5,6,7,5,6,7,6,7,7};

union U8 { short8 v; unsigned short u[8]; };
union CV { uint4 q; short8 v; };

template<bool BF, int MODE>
__device__ __forceinline__ void mlp_mfma_body(
    const void* evec,
    const void* wain, const void* bain, const void* ga1p, const void* bea1p,
    const void* wam,  const void* bam,  const void* ga2p, const void* bea2p,
    const void* wao,  const void* bao,
    const float* a1buf, float* outbuf, unsigned short* hbuf)
{
    const int tid  = threadIdx.x;
    const int lane = tid & 63;
    const int wsl  = tid >> 6;
    const int col  = lane & 15;
    const int quad = lane >> 4;
    unsigned short* hslice = hbuf + wsl * 1024;
    const int widx = MODE;
    const int nbatch  = (MODE == 0) ? NB1 : NB2;
    const int gw      = blockIdx.x * 4 + wsl;
    const int gstride = gridDim.x * 4;

    // ---- persistent weight fragments ----
    U8 w1f[4][4];                       // [k-step q][n-tile]
    #pragma unroll
    for (int q = 0; q < 4; ++q)
        #pragma unroll
        for (int n = 0; n < 4; ++n)
            #pragma unroll
            for (int j = 0; j < 8; ++j)
                w1f[q][n].u[j] = LDB<BF>(wain,
                    (size_t)widx*8192 + (size_t)(q*32 + quad*8 + j)*64 + n*16 + col);
    U8 w2f[2][4];
    #pragma unroll
    for (int q = 0; q < 2; ++q)
        #pragma unroll
        for (int n = 0; n < 4; ++n)
            #pragma unroll
            for (int j = 0; j < 8; ++j)
                w2f[q][n].u[j] = LDB<BF>(wam,
                    (size_t)widx*4096 + (size_t)(q*32 + quad*8 + j)*64 + n*16 + col);
    float w3r[4][4];                    // [t][hh] = W3[t*16+col][hh]
    #pragma unroll
    for (int t = 0; t < 4; ++t)
        #pragma unroll
        for (int hh = 0; hh < 4; ++hh)
            w3r[t][hh] = LD<BF>(wao, (size_t)widx*256 + (size_t)(t*16 + col)*4 + hh);
    float b1r[4], g1r[4], be1r[4], b2r[4], g2r[4], be2r[4], b3r[4];
    #pragma unroll
    for (int t = 0; t < 4; ++t) {
        int n = t*16 + col;
        b1r[t]  = LD<BF>(bain,  (size_t)widx*64 + n);
        g1r[t]  = LD<BF>(ga1p,  (size_t)widx*64 + n);
        be1r[t] = LD<BF>(bea1p, (size_t)widx*64 + n);
        b2r[t]  = LD<BF>(bam,   (size_t)widx*64 + n);
        g2r[t]  = LD<BF>(ga2p,  (size_t)widx*64 + n);
        be2r[t] = LD<BF>(bea2p, (size_t)widx*64 + n);
    }
    #pragma unroll
    for (int hh = 0; hh < 4; ++hh) b3r[hh] = LD<BF>(bao, (size_t)widx*4 + hh);

    for (int bb = gw; bb < nbatch; bb += gstride) {
        const int base = bb * 16;
        // ---- per-task scalar d (lanes 0..15 hold tasks 0..15) ----
        float dval = 0.f; int eaL = 0, ebL = 0, aL = 0, bL = 0;
        if (lane < 16) {
            if (MODE == 0) {
                int e = base + lane;
                float vx = LD<BF>(evec, (size_t)e*3+0);
                float vy = LD<BF>(evec, (size_t)e*3+1);
                float vz = LD<BF>(evec, (size_t)e*3+2);
                dval = sqrtf(vx*vx + vy*vy + vz*vz);
            } else {
                int task = base + lane;
                int i = task / NPAIR;
                int u = task - i * NPAIR;
                aL = UA[u]; bL = UB[u];
                eaL = i*8 + aL; ebL = i*8 + bL;
                float ax = LD<BF>(evec,(size_t)eaL*3+0), ay = LD<BF>(evec,(size_t)eaL*3+1), az = LD<BF>(evec,(size_t)eaL*3+2);
                float bx = LD<BF>(evec,(size_t)ebL*3+0), by = LD<BF>(evec,(size_t)ebL*3+1), bz = LD<BF>(evec,(size_t)ebL*3+2);
                float dx = bx-ax, dy = by-ay, dz = bz-az;
                dval = sqrtf(dx*dx + dy*dy + dz*dz);
            }
        }
        float dm = __shfl(dval, col, 64);   // d of task m = col (A-frag row)

        // ---- layer 1: X @ W1, X computed in-register in A-frag layout ----
        acc4 ac0 = {0.f,0.f,0.f,0.f}, ac1 = ac0, ac2 = ac0, ac3 = ac0;
        #pragma unroll
        for (int q = 0; q < 4; ++q) {
            U8 af;
            #pragma unroll
            for (int j = 0; j < 8; ++j) {
                float c = (float)(q*32 + quad*8 + j) * GSTEP;
                float t = dm - c;
                af.u[j] = f2b(__expf(-(t*t) * GINV));
            }
            ac0 = __builtin_amdgcn_mfma_f32_16x16x32_bf16(af.v, w1f[q][0].v, ac0, 0,0,0);
            ac1 = __builtin_amdgcn_mfma_f32_16x16x32_bf16(af.v, w1f[q][1].v, ac1, 0,0,0);
            ac2 = __builtin_amdgcn_mfma_f32_16x16x32_bf16(af.v, w1f[q][2].v, ac2, 0,0,0);
            ac3 = __builtin_amdgcn_mfma_f32_16x16x32_bf16(af.v, w1f[q][3].v, ac3, 0,0,0);
        }
        // ---- LN1 + SiLU (per task m = quad*4+r; sum over n = t*16+col) ----
        float val[4][4];    // [t][r]
        #pragma unroll
        for (int r = 0; r < 4; ++r) {
            val[0][r] = ac0[r] + b1r[0];
            val[1][r] = ac1[r] + b1r[1];
            val[2][r] = ac2[r] + b1r[2];
            val[3][r] = ac3[r] + b1r[3];
        }
        float sr[4], sq[4];
        #pragma unroll
        for (int r = 0; r < 4; ++r) {
            sr[r] = val[0][r] + val[1][r] + val[2][r] + val[3][r];
            sq[r] = val[0][r]*val[0][r] + val[1][r]*val[1][r]
                  + val[2][r]*val[2][r] + val[3][r]*val[3][r];
        }
        #pragma unroll
        for (int mm = 1; mm < 16; mm <<= 1)
            #pragma unroll
            for (int r = 0; r < 4; ++r) {
                sr[r] += __shfl_xor(sr[r], mm, 64);
                sq[r] += __shfl_xor(sq[r], mm, 64);
            }
        #pragma unroll
        for (int r = 0; r < 4; ++r) {
            float mu  = sr[r] * (1.0f/64.0f);
            float var = sq[r] * (1.0f/64.0f) - mu*mu;
            float inv = rsqrtf(var + 1e-6f);
            #pragma unroll
            for (int t = 0; t < 4; ++t) {
                float x = (val[t][r] - mu) * inv * g1r[t] + be1r[t];
                x = x * (1.0f / (1.0f + __expf(-x)));
                int m = quad*4 + r;
                int n = t*16 + col;
                hslice[m*64 + (n ^ ((m & 7) * 8))] = f2b(x);   // XOR bank swizzle
            }
        }
        __syncthreads();
        // ---- layer 2: H1 @ W2 (A-frag read from swizzled LDS) ----
        acc4 bc0 = {0.f,0.f,0.f,0.f}, bc1 = bc0, bc2 = bc0, bc3 = bc0;
        #pragma unroll
        for (int q = 0; q < 2; ++q) {
            int nbase = (q*32 + quad*8) ^ ((col & 7) * 8);
            CV cv; cv.q = *(const uint4*)(&hslice[col*64 + nbase]);
            bc0 = __builtin_amdgcn_mfma_f32_16x16x32_bf16(cv.v, w2f[q][0].v, bc0, 0,0,0);
            bc1 = __builtin_amdgcn_mfma_f32_16x16x32_bf16(cv.v, w2f[q][1].v, bc1, 0,0,0);
            bc2 = __builtin_amdgcn_mfma_f32_16x16x32_bf16(cv.v, w2f[q][2].v, bc2, 0,0,0);
            bc3 = __builtin_amdgcn_mfma_f32_16x16x32_bf16(cv.v, w2f[q][3].v, bc3, 0,0,0);
        }
        __syncthreads();   // hslice reusable next iteration
        // ---- LN2 + SiLU ----
        float h2[4][4];    // [t][r]
        #pragma unroll
        for (int r = 0; r < 4; ++r) {
            h2[0][r] = bc0[r] + b2r[0];
            h2[1][r] = bc1[r] + b2r[1];
            h2[2][r] = bc2[r] + b2r[2];
            h2[3][r] = bc3[r] + b2r[3];
        }
        #pragma unroll
        for (int r = 0; r < 4; ++r) {
            sr[r] = h2[0][r] + h2[1][r] + h2[2][r] + h2[3][r];
            sq[r] = h2[0][r]*h2[0][r] + h2[1][r]*h2[1][r]
                  + h2[2][r]*h2[2][r] + h2[3][r]*h2[3][r];
        }
        #pragma unroll
        for (int mm = 1; mm < 16; mm <<= 1)
            #pragma unroll
            for (int r = 0; r < 4; ++r) {
                sr[r] += __shfl_xor(sr[r], mm, 64);
                sq[r] += __shfl_xor(sq[r], mm, 64);
            }
        #pragma unroll
        for (int r = 0; r < 4; ++r) {
            float mu  = sr[r] * (1.0f/64.0f);
            float var = sq[r] * (1.0f/64.0f) - mu*mu;
            float inv = rsqrtf(var + 1e-6f);
            #pragma unroll
            for (int t = 0; t < 4; ++t) {
                float x = (h2[t][r] - mu) * inv * g2r[t] + be2r[t];
                h2[t][r] = x * (1.0f / (1.0f + __expf(-x)));
            }
        }
        // ---- layer 3: 64 -> 4 (VALU partials + 16-lane shuffle reduce) ----
        float p[4][4];     // [r][hh]
        #pragma unroll
        for (int r = 0; r < 4; ++r)
            #pragma unroll
            for (int hh = 0; hh < 4; ++hh)
                p[r][hh] = h2[0][r]*w3r[0][hh] + h2[1][r]*w3r[1][hh]
                         + h2[2][r]*w3r[2][hh] + h2[3][r]*w3r[3][hh];
        #pragma unroll
        for (int mm = 1; mm < 16; mm <<= 1)
            #pragma unroll
            for (int r = 0; r < 4; ++r)
                #pragma unroll
                for (int hh = 0; hh < 4; ++hh)
                    p[r][hh] += __shfl_xor(p[r][hh], mm, 64);

        // ---- output (writer lanes: col<4 handle task m = quad*4+col) ----
        if (MODE == 0) {
            if (col < 4) {
                int m = quad*4 + col;
                int e = base + m;
                float o0 = p[0][0], o1 = p[0][1], o2 = p[0][2], o3 = p[0][3];
                if (col == 1) { o0 = p[1][0]; o1 = p[1][1]; o2 = p[1][2]; o3 = p[1][3]; }
                if (col == 2) { o0 = p[2][0]; o1 = p[2][1]; o2 = p[2][2]; o3 = p[2][3]; }
                if (col == 3) { o0 = p[3][0]; o1 = p[3][1]; o2 = p[3][2]; o3 = p[3][3]; }
                float4 o; o.x = o0 + b3r[0]; o.y = o1 + b3r[1]; o.z = o2 + b3r[2]; o.w = o3 + b3r[3];
                *(float4*)(&outbuf[(size_t)e*4]) = o;
            }
        } else {
            int m0  = quad*4 + (col & 3);
            int eaW = __shfl(eaL, m0, 64);
            int ebW = __shfl(ebL, m0, 64);
            int aW  = __shfl(aL,  m0, 64);
            int bW  = __shfl(bL,  m0, 64);
            if (col < 4) {
                float o0 = p[0][0], o1 = p[0][1], o2 = p[0][2], o3 = p[0][3];
                if (col == 1) { o0 = p[1][0]; o1 = p[1][1]; o2 = p[1][2]; o3 = p[1][3]; }
                if (col == 2) { o0 = p[2][0]; o1 = p[2][1]; o2 = p[2][2]; o3 = p[2][3]; }
                if (col == 3) { o0 = p[3][0]; o1 = p[3][1]; o2 = p[3][2]; o3 = p[3][3]; }
                o0 += b3r[0]; o1 += b3r[1]; o2 += b3r[2]; o3 += b3r[3];
                float4 g = *(const float4*)(&a1buf[(size_t)ebW*4]);   // src = eb
                float4 r1; r1.x = o0*g.x; r1.y = o1*g.y; r1.z = o2*g.z; r1.w = o3*g.w;
                *(float4*)(&outbuf[(size_t)(eaW*8 + bW)*4]) = r1;
                if (aW != bW) {
                    float4 g2 = *(const float4*)(&a1buf[(size_t)eaW*4]); // src = ea
                    float4 r2; r2.x = o0*g2.x; r2.y = o1*g2.y; r2.z = o2*g2.z; r2.w = o3*g2.w;
                    *(float4*)(&outbuf[(size_t)(ebW*8 + aW)*4]) = r2;
                }
            }
        }
    }
}

__global__ __launch_bounds__(256, 2) void k_mlp1(
    const int* __restrict__ flag, const void* evec,
    const void* wain, const void* bain, const void* ga1p, const void* bea1p,
    const void* wam,  const void* bam,  const void* ga2p, const void* bea2p,
    const void* wao,  const void* bao, float* __restrict__ a1buf)
{
    __shared__ __align__(16) unsigned short hbuf[4096];
    if (*flag) mlp_mfma_body<true ,0>(evec, wain, bain, ga1p, bea1p, wam, bam, ga2p, bea2p,
                                      wao, bao, nullptr, a1buf, hbuf);
    else       mlp_mfma_body<false,0>(evec, wain, bain, ga1p, bea1p, wam, bam, ga2p, bea2p,
                                      wao, bao, nullptr, a1buf, hbuf);
}

__global__ __launch_bounds__(256, 2) void k_mlp2(
    const int* __restrict__ flag, const void* evec,
    const void* wain, const void* bain, const void* ga1p, const void* bea1p,
    const void* wam,  const void* bam,  const void* ga2p, const void* bea2p,
    const void* wao,  const void* bao,
    const float* __restrict__ a1buf, float* __restrict__ alpha)
{
    __shared__ __align__(16) unsigned short hbuf[4096];
    if (*flag) mlp_mfma_body<true ,1>(evec, wain, bain, ga1p, bea1p, wam, bam, ga2p, bea2p,
                                      wao, bao, a1buf, alpha, hbuf);
    else       mlp_mfma_body<false,1>(evec, wain, bain, ga1p, bea1p, wam, bam, ga2p, bea2p,
                                      wao, bao, a1buf, alpha, hbuf);
}

// ---------------------------------------------------------------------------
// Kernel 4: per target edge e: softmax over its 8 triplets (per head), aggregate
// value rows, apply W_lin -> eout[e,0..63] (stored bf16). Wave per edge.
template<bool BF> __device__ __forceinline__ void edge_body(
    const float* alpha, const unsigned short* value,
    const int* src_eid, const int* inv_index,
    const void* wlin, unsigned short* eout,
    float* WL, float* alsb, float* feab)
{
    const int tid = threadIdx.x;
    for (int i = tid; i < 8192; i += 256) WL[i] = LD<BF>(wlin, (size_t)i);
    __syncthreads();
    const int lane = tid & 63, ws = tid >> 6;
    float* als = alsb + ws * 32;
    float* fea = feab + ws * 128;
    for (int base = blockIdx.x * 4; base < EE; base += gridDim.x * 4) {
        int e = base + ws;
        float v = -1e30f;
        if (lane < 32) v = alpha[(size_t)e*32 + lane];   // lane = b*4+h
        float vm = v;
        vm = fmaxf(vm, __shfl_xor(vm, 4, 64));
        vm = fmaxf(vm, __shfl_xor(vm, 8, 64));
        vm = fmaxf(vm, __shfl_xor(vm, 16, 64));
        float ex = __expf(v - vm);
        float den = ex;
        den += __shfl_xor(den, 4, 64);
        den += __shfl_xor(den, 8, 64);
        den += __shfl_xor(den, 16, 64);
        float al = ex / (den + 1e-16f);
        if (lane < 32) als[lane] = al;
        __syncthreads();
        float f0 = 0.f, f1 = 0.f;
        int h0 = lane >> 5;
        #pragma unroll
        for (int bq = 0; bq < 8; ++bq) {
            int se = src_eid[e*8 + bq];
            int row = inv_index[se];
            const unsigned short* vr = &value[(size_t)row * FF];
            f0 += als[bq*4 + h0]     * b2f(vr[lane]);
            f1 += als[bq*4 + h0 + 2] * b2f(vr[64 + lane]);
        }
        fea[lane] = f0; fea[64 + lane] = f1;
        __syncthreads();
        float acc = 0.f;
        #pragma unroll
        for (int f = 0; f < 128; f += 4) {
            float4 fe = *(const float4*)(&fea[f]);
            acc += fe.x * WL[(f+0)*64 + lane];
            acc += fe.y * WL[(f+1)*64 + lane];
            acc += fe.z * WL[(f+2)*64 + lane];
            acc += fe.w * WL[(f+3)*64 + lane];
        }
        eout[(size_t)e*64 + lane] = f2b(acc);
    }
}

__global__ __launch_bounds__(256) void k_edge(
    const int* __restrict__ flag,
    const float* __restrict__ alpha, const unsigned short* __restrict__ value,
    const int* __restrict__ src_eid, const int* __restrict__ inv_index,
    const void* wlin, unsigned short* __restrict__ eout)
{
    __shared__ float WL[128*64];
    __shared__ float alsb[4*32];
    __shared__ float feab[4*128];
    if (*flag) edge_body<true >(alpha, value, src_eid, inv_index, wlin, eout, WL, alsb, feab);
    else       edge_body<false>(alpha, value, src_eid, inv_index, wlin, eout, WL, alsb, feab);
}

// ---------------------------------------------------------------------------
// Kernel 5: node_out[n,o] = sum_s eout[inv_index[n*8+s], o]; output dtype per flag.
__global__ __launch_bounds__(256) void k_node(
    const int* __restrict__ flag, const unsigned short* __restrict__ eout,
    const int* __restrict__ inv_index, void* __restrict__ out)
{
    int gid = blockIdx.x * 256 + threadIdx.x;   // exactly N*64 = 512000
    int n = gid >> 6, o = gid & 63;
    float s = 0.f;
    #pragma unroll
    for (int q = 0; q < 8; ++q) {
        int row = inv_index[n*8 + q];
        s += b2f(eout[(size_t)row*64 + o]);
    }
    if (*flag) ((unsigned short*)out)[gid] = f2b(s);
    else       ((float*)out)[gid] = s;
}

// ---------------------------------------------------------------------------
extern "C" void kernel_launch(void* const* d_in, const int* in_sizes, int n_in,
                              void* d_out, int out_size, void* d_ws, size_t ws_size,
                              hipStream_t stream)
{
    const void* ein  = d_in[0];
    const void* esh  = d_in[1];
    const void* elem = d_in[2];
    const void* evec = d_in[3];
    const void* wtp  = d_in[4];
    const void* wrad = d_in[5];
    const void* wlin = d_in[6];
    const void* wain = d_in[7];
    const void* bain = d_in[8];
    const void* ga1p = d_in[9];
    const void* bea1p= d_in[10];
    const void* wam  = d_in[11];
    const void* bam  = d_in[12];
    const void* ga2p = d_in[13];
    const void* bea2p= d_in[14];
    const void* wao  = d_in[15];
    const void* bao  = d_in[16];
    const int* inv_index = (const int*)d_in[17];
    const int* src_eid   = (const int*)d_in[19];

    // workspace layout (33.8 MB total), all offsets 16B-aligned
    char* ws = (char*)d_ws;
    int*            flag  = (int*)ws;                               // 16 B
    unsigned short* value = (unsigned short*)(ws + 16);             // E*128*2
    float*          a1buf = (float*)(ws + 16 + 16384000);           // E*4*4
    float*          alpha = (float*)(ws + 16 + 16384000 + 1024000); // T*4*4
    unsigned short* eoutb = (unsigned short*)(ws + 16 + 16384000 + 1024000 + 8192000); // E*64*2

    hipLaunchKernelGGL(k_detect, dim3(1), dim3(64), 0, stream, esh, flag);
    hipLaunchKernelGGL(k_value,  dim3(EE/16), dim3(128), 0, stream,
                       flag, ein, esh, elem, wtp, wrad, value);
    hipLaunchKernelGGL(k_mlp1,   dim3(250),  dim3(256), 0, stream,
                       flag, evec, wain, bain, ga1p, bea1p, wam, bam, ga2p, bea2p, wao, bao, a1buf);
    hipLaunchKernelGGL(k_mlp2,   dim3(500),  dim3(256), 0, stream,
                       flag, evec, wain, bain, ga1p, bea1p, wam, bam, ga2p, bea2p, wao, bao,
                       a1buf, alpha);
    hipLaunchKernelGGL(k_edge,   dim3(1024), dim3(256), 0, stream,
                       flag, alpha, value, src_eid, inv_index, wlin, eoutb);
    hipLaunchKernelGGL(k_node,   dim3((NN*CO)/256), dim3(256), 0, stream,
                       flag, eoutb, inv_index, d_out);
}

// Round 8
// 434.357 us; speedup vs baseline: 2.6056x; 1.0576x over previous
//
#include <hip/hip_runtime.h>
#include <math.h>

// Problem constants (fixed by reference). Inputs/outputs are FP32 (validated:
// rounds 2-3 passed on the fp32 branch). Precision config (round 7, accuracy-
// validated at absmax 6.84e-3):
//   k_value: compensated fp16 MFMA (hi/lo split, 3 MFMAs) -> ~fp32-exact einsum
//   MLPs:    single fp16 MFMA; stores: value/eout fp16, alpha/a1 fp32, out fp32
// Round 8: k_value restructured to <=48KB LDS (was 156KB) -- suspect of the
// round-7 graph-replay tripwire divergence. Same arithmetic, chunked staging.
#define NN 8000
#define KK 8
#define EE (NN*KK)        // 64000 edges
#define TT (EE*KK)        // 512000 triplets
#define CC 32
#define SS 9
#define FF 128
#define BB 128
#define CO 64
#define NPAIR 36          // unique (a<=b) pairs of 8 slots
#define NTASK (NN*NPAIR)  // 288000 unique a2-MLP evals
#define NB1 (EE/16)       // 4000 batches of 16 edges
#define NB2 (NTASK/16)    // 18000 batches of 16 pair-tasks

// Gaussian expansion: centers k*6/127, width = 3/128 -> 1/(2w^2) = 8192/9
#define GSTEP (6.0f/127.0f)
#define GINV  (8192.0f/9.0f)

typedef __attribute__((ext_vector_type(8))) _Float16 half8;
typedef __attribute__((ext_vector_type(4))) float acc4;

__device__ __forceinline__ unsigned short f2h(float f) {
    _Float16 h = (_Float16)f;                 // RNE
    return *(unsigned short*)&h;
}
__device__ __forceinline__ float h2f(unsigned short u) {
    _Float16 h = *(_Float16*)&u;
    return (float)h;
}

union H8 { half8 v; unsigned short u[8]; };
union CV { uint4 q; half8 v; };

// ---------------------------------------------------------------------------
// Kernel 1 (compensated fp16 MFMA, chunked staging, 48KB LDS):
// value[e,f] = (sum_cs (ein[e,c]*esh[e,s]) * Wtp[c,s,f]) * (elem[e,:] @ Wrad[:,f])
// 64 edges/block, 256 threads = 4 waves; wave w owns the 16-edge tile w.
// Operands split hi/lo fp16; D = Ahi*Bhi + Ahi*Blo + Alo*Bhi (fp32 accum).
// Weights staged fragment-linear [kstep][nt][lane][8] -> conflict-free b128.
// A-operands (ein/esh/elem rows) read per-lane directly from global fp32.
__global__ __launch_bounds__(256, 1) void k_value(
    const float* __restrict__ ein, const float* __restrict__ esh,
    const float* __restrict__ elem, const float* __restrict__ wtp,
    const float* __restrict__ wrad, unsigned short* __restrict__ value)
{
    __shared__ __align__(16) unsigned short sW[2][3*8*64*8];   // 49152 bytes
    const int tid  = threadIdx.x;
    const int lane = tid & 63;
    const int wv   = tid >> 6;
    const int col  = lane & 15;
    const int quad = lane >> 4;
    const int e0   = blockIdx.x * 64;
    const int erowA = e0 + wv*16 + col;     // edge this lane's A-row refers to

    // ---- per-lane fp32 A-operands from global (exact) ----
    float einr[8];
    #pragma unroll
    for (int j = 0; j < 8; ++j) einr[j] = ein[(size_t)erowA*CC + quad*8 + j];
    float eshr[9];
    #pragma unroll
    for (int s = 0; s < 9; ++s) eshr[s] = esh[(size_t)erowA*SS + s];

    // ---- phase 1: P = (ein (x) esh) @ Wtp, K=288 = 9 s-steps of 32, 3 chunks ----
    acc4 macc[8];
    #pragma unroll
    for (int nt = 0; nt < 8; ++nt) macc[nt] = (acc4){0.f,0.f,0.f,0.f};

    for (int cch = 0; cch < 3; ++cch) {
        if (cch) __syncthreads();           // protect prior chunk's reads
        for (int i = tid; i < 3*32*128; i += 256) {   // stage Wtp s in {3cch..+2}
            int sl  = i >> 12;              // 0..2
            int rem = i & 4095;
            int ch  = rem >> 7;             // channel 0..31
            int f   = rem & 127;
            int s   = cch*3 + sl;
            float w = wtp[((size_t)ch*SS + s)*FF + f];
            unsigned short hi = f2h(w);
            int pos = ((sl*8 + (f>>4))*64 + ((ch>>3)*16 + (f&15)))*8 + (ch&7);
            sW[0][pos] = hi;
            sW[1][pos] = f2h(w - h2f(hi));
        }
        __syncthreads();
        #pragma unroll
        for (int sl = 0; sl < 3; ++sl) {
            int s = cch*3 + sl;
            H8 ahi, alo;
            #pragma unroll
            for (int j = 0; j < 8; ++j) {
                float p = einr[j] * eshr[s];
                unsigned short h = f2h(p);
                ahi.u[j] = h;
                alo.u[j] = f2h(p - h2f(h));
            }
            #pragma unroll
            for (int nt = 0; nt < 8; ++nt) {
                CV chv; chv.q = *(const uint4*)(&sW[0][((sl*8 + nt)*64 + lane)*8]);
                CV clv; clv.q = *(const uint4*)(&sW[1][((sl*8 + nt)*64 + lane)*8]);
                macc[nt] = __builtin_amdgcn_mfma_f32_16x16x32_f16(ahi.v, chv.v, macc[nt], 0,0,0);
                macc[nt] = __builtin_amdgcn_mfma_f32_16x16x32_f16(ahi.v, clv.v, macc[nt], 0,0,0);
                macc[nt] = __builtin_amdgcn_mfma_f32_16x16x32_f16(alo.v, chv.v, macc[nt], 0,0,0);
            }
        }
    }

    // ---- phase 2: R = elem @ Wrad, K=128 = 4 k-steps of 32, 2 chunks ----
    acc4 racc[8];
    #pragma unroll
    for (int nt = 0; nt < 8; ++nt) racc[nt] = (acc4){0.f,0.f,0.f,0.f};

    for (int kc = 0; kc < 2; ++kc) {
        __syncthreads();                    // protect prior reads before overwrite
        for (int i = tid; i < 2*32*128; i += 256) {   // stage Wrad ksteps {2kc,2kc+1}
            int l   = i >> 12;              // 0..1
            int rem = i & 4095;
            int kr  = rem >> 7;             // 0..31
            int f   = rem & 127;
            int k   = (kc*2 + l)*32 + kr;
            float w = wrad[(size_t)k*FF + f];
            unsigned short hi = f2h(w);
            int pos = ((l*8 + (f>>4))*64 + ((kr>>3)*16 + (f&15)))*8 + (kr&7);
            sW[0][pos] = hi;
            sW[1][pos] = f2h(w - h2f(hi));
        }
        __syncthreads();
        #pragma unroll
        for (int l = 0; l < 2; ++l) {
            int ks = kc*2 + l;
            H8 ahi, alo;
            #pragma unroll
            for (int j = 0; j < 8; ++j) {
                float p = elem[(size_t)erowA*BB + ks*32 + quad*8 + j];
                unsigned short h = f2h(p);
                ahi.u[j] = h;
                alo.u[j] = f2h(p - h2f(h));
            }
            #pragma unroll
            for (int nt = 0; nt < 8; ++nt) {
                CV chv; chv.q = *(const uint4*)(&sW[0][((l*8 + nt)*64 + lane)*8]);
                CV clv; clv.q = *(const uint4*)(&sW[1][((l*8 + nt)*64 + lane)*8]);
                racc[nt] = __builtin_amdgcn_mfma_f32_16x16x32_f16(ahi.v, chv.v, racc[nt], 0,0,0);
                racc[nt] = __builtin_amdgcn_mfma_f32_16x16x32_f16(ahi.v, clv.v, racc[nt], 0,0,0);
                racc[nt] = __builtin_amdgcn_mfma_f32_16x16x32_f16(alo.v, chv.v, racc[nt], 0,0,0);
            }
        }
    }

    // ---- multiply & store fp16 (D layout: row=quad*4+r, col per tile) ----
    #pragma unroll
    for (int r = 0; r < 4; ++r) {
        int erow = e0 + wv*16 + quad*4 + r;
        #pragma unroll
        for (int nt = 0; nt < 8; ++nt)
            value[(size_t)erow*FF + nt*16 + col] = f2h(macc[nt][r] * racc[nt][r]);
    }
}

// ---------------------------------------------------------------------------
// MFMA-batched MLP: 16 tasks per wave; fp16 operands, fp32 LN/softmax math.
__device__ const int UA[NPAIR] = {0,0,0,0,0,0,0,0,1,1,1,1,1,1,1,2,2,2,2,2,2,3,3,3,3,3,4,4,4,4,5,5,5,6,6,7};
__device__ const int UB[NPAIR] = {0,1,2,3,4,5,6,7,1,2,3,4,5,6,7,2,3,4,5,6,7,3,4,5,6,7,4,5,6,7,5,6,7,6,7,7};

template<int MODE>
__device__ __forceinline__ void mlp_mfma_body(
    const float* __restrict__ evec,
    const float* __restrict__ wain, const float* __restrict__ bain,
    const float* __restrict__ ga1p, const float* __restrict__ bea1p,
    const float* __restrict__ wam,  const float* __restrict__ bam,
    const float* __restrict__ ga2p, const float* __restrict__ bea2p,
    const float* __restrict__ wao,  const float* __restrict__ bao,
    const float* a1buf, float* outbuf, unsigned short* hbuf)
{
    const int tid  = threadIdx.x;
    const int lane = tid & 63;
    const int wsl  = tid >> 6;
    const int col  = lane & 15;
    const int quad = lane >> 4;
    unsigned short* hslice = hbuf + wsl * 1024;
    const int widx = MODE;
    const int nbatch  = (MODE == 0) ? NB1 : NB2;
    const int gw      = blockIdx.x * 4 + wsl;
    const int gstride = gridDim.x * 4;

    H8 w1f[4][4];
    #pragma unroll
    for (int q = 0; q < 4; ++q)
        #pragma unroll
        for (int n = 0; n < 4; ++n)
            #pragma unroll
            for (int j = 0; j < 8; ++j)
                w1f[q][n].u[j] = f2h(wain[(size_t)widx*8192 + (size_t)(q*32 + quad*8 + j)*64 + n*16 + col]);
    H8 w2f[2][4];
    #pragma unroll
    for (int q = 0; q < 2; ++q)
        #pragma unroll
        for (int n = 0; n < 4; ++n)
            #pragma unroll
            for (int j = 0; j < 8; ++j)
                w2f[q][n].u[j] = f2h(wam[(size_t)widx*4096 + (size_t)(q*32 + quad*8 + j)*64 + n*16 + col]);
    float w3r[4][4];
    #pragma unroll
    for (int t = 0; t < 4; ++t)
        #pragma unroll
        for (int hh = 0; hh < 4; ++hh)
            w3r[t][hh] = wao[(size_t)widx*256 + (size_t)(t*16 + col)*4 + hh];
    float b1r[4], g1r[4], be1r[4], b2r[4], g2r[4], be2r[4], b3r[4];
    #pragma unroll
    for (int t = 0; t < 4; ++t) {
        int n = t*16 + col;
        b1r[t]  = bain [widx*64 + n];
        g1r[t]  = ga1p [widx*64 + n];
        be1r[t] = bea1p[widx*64 + n];
        b2r[t]  = bam  [widx*64 + n];
        g2r[t]  = ga2p [widx*64 + n];
        be2r[t] = bea2p[widx*64 + n];
    }
    #pragma unroll
    for (int hh = 0; hh < 4; ++hh) b3r[hh] = bao[widx*4 + hh];

    for (int bb = gw; bb < nbatch; bb += gstride) {
        const int base = bb * 16;
        float dval = 0.f; int eaL = 0, ebL = 0, aL = 0, bL = 0;
        if (lane < 16) {
            if (MODE == 0) {
                int e = base + lane;
                float vx = evec[e*3+0], vy = evec[e*3+1], vz = evec[e*3+2];
                dval = sqrtf(vx*vx + vy*vy + vz*vz);
            } else {
                int task = base + lane;
                int i = task / NPAIR;
                int u = task - i * NPAIR;
                aL = UA[u]; bL = UB[u];
                eaL = i*8 + aL; ebL = i*8 + bL;
                float dx = evec[ebL*3+0] - evec[eaL*3+0];
                float dy = evec[ebL*3+1] - evec[eaL*3+1];
                float dz = evec[ebL*3+2] - evec[eaL*3+2];
                dval = sqrtf(dx*dx + dy*dy + dz*dz);
            }
        }
        float dm = __shfl(dval, col, 64);

        acc4 ac0 = {0.f,0.f,0.f,0.f}, ac1 = ac0, ac2 = ac0, ac3 = ac0;
        #pragma unroll
        for (int q = 0; q < 4; ++q) {
            H8 afr;
            #pragma unroll
            for (int j = 0; j < 8; ++j) {
                float c = (float)(q*32 + quad*8 + j) * GSTEP;
                float t = dm - c;
                afr.u[j] = f2h(__expf(-(t*t) * GINV));
            }
            ac0 = __builtin_amdgcn_mfma_f32_16x16x32_f16(afr.v, w1f[q][0].v, ac0, 0,0,0);
            ac1 = __builtin_amdgcn_mfma_f32_16x16x32_f16(afr.v, w1f[q][1].v, ac1, 0,0,0);
            ac2 = __builtin_amdgcn_mfma_f32_16x16x32_f16(afr.v, w1f[q][2].v, ac2, 0,0,0);
            ac3 = __builtin_amdgcn_mfma_f32_16x16x32_f16(afr.v, w1f[q][3].v, ac3, 0,0,0);
        }
        float val[4][4];
        #pragma unroll
        for (int r = 0; r < 4; ++r) {
            val[0][r] = ac0[r] + b1r[0];
            val[1][r] = ac1[r] + b1r[1];
            val[2][r] = ac2[r] + b1r[2];
            val[3][r] = ac3[r] + b1r[3];
        }
        float sr[4], sq[4];
        #pragma unroll
        for (int r = 0; r < 4; ++r) {
            sr[r] = val[0][r] + val[1][r] + val[2][r] + val[3][r];
            sq[r] = val[0][r]*val[0][r] + val[1][r]*val[1][r]
                  + val[2][r]*val[2][r] + val[3][r]*val[3][r];
        }
        #pragma unroll
        for (int mm = 1; mm < 16; mm <<= 1)
            #pragma unroll
            for (int r = 0; r < 4; ++r) {
                sr[r] += __shfl_xor(sr[r], mm, 64);
                sq[r] += __shfl_xor(sq[r], mm, 64);
            }
        #pragma unroll
        for (int r = 0; r < 4; ++r) {
            float mu  = sr[r] * (1.0f/64.0f);
            float var = sq[r] * (1.0f/64.0f) - mu*mu;
            float inv = rsqrtf(var + 1e-6f);
            #pragma unroll
            for (int t = 0; t < 4; ++t) {
                float x = (val[t][r] - mu) * inv * g1r[t] + be1r[t];
                x = x * (1.0f / (1.0f + __expf(-x)));
                int m = quad*4 + r;
                int n = t*16 + col;
                hslice[m*64 + (n ^ ((m & 7) * 8))] = f2h(x);   // XOR bank swizzle
            }
        }
        __syncthreads();
        acc4 bc0 = {0.f,0.f,0.f,0.f}, bc1 = bc0, bc2 = bc0, bc3 = bc0;
        #pragma unroll
        for (int q = 0; q < 2; ++q) {
            int nbase = (q*32 + quad*8) ^ ((col & 7) * 8);
            CV cv; cv.q = *(const uint4*)(&hslice[col*64 + nbase]);
            bc0 = __builtin_amdgcn_mfma_f32_16x16x32_f16(cv.v, w2f[q][0].v, bc0, 0,0,0);
            bc1 = __builtin_amdgcn_mfma_f32_16x16x32_f16(cv.v, w2f[q][1].v, bc1, 0,0,0);
            bc2 = __builtin_amdgcn_mfma_f32_16x16x32_f16(cv.v, w2f[q][2].v, bc2, 0,0,0);
            bc3 = __builtin_amdgcn_mfma_f32_16x16x32_f16(cv.v, w2f[q][3].v, bc3, 0,0,0);
        }
        __syncthreads();
        float h2[4][4];
        #pragma unroll
        for (int r = 0; r < 4; ++r) {
            h2[0][r] = bc0[r] + b2r[0];
            h2[1][r] = bc1[r] + b2r[1];
            h2[2][r] = bc2[r] + b2r[2];
            h2[3][r] = bc3[r] + b2r[3];
        }
        #pragma unroll
        for (int r = 0; r < 4; ++r) {
            sr[r] = h2[0][r] + h2[1][r] + h2[2][r] + h2[3][r];
            sq[r] = h2[0][r]*h2[0][r] + h2[1][r]*h2[1][r]
                  + h2[2][r]*h2[2][r] + h2[3][r]*h2[3][r];
        }
        #pragma unroll
        for (int mm = 1; mm < 16; mm <<= 1)
            #pragma unroll
            for (int r = 0; r < 4; ++r) {
                sr[r] += __shfl_xor(sr[r], mm, 64);
                sq[r] += __shfl_xor(sq[r], mm, 64);
            }
        #pragma unroll
        for (int r = 0; r < 4; ++r) {
            float mu  = sr[r] * (1.0f/64.0f);
            float var = sq[r] * (1.0f/64.0f) - mu*mu;
            float inv = rsqrtf(var + 1e-6f);
            #pragma unroll
            for (int t = 0; t < 4; ++t) {
                float x = (h2[t][r] - mu) * inv * g2r[t] + be2r[t];
                h2[t][r] = x * (1.0f / (1.0f + __expf(-x)));
            }
        }
        float p[4][4];
        #pragma unroll
        for (int r = 0; r < 4; ++r)
            #pragma unroll
            for (int hh = 0; hh < 4; ++hh)
                p[r][hh] = h2[0][r]*w3r[0][hh] + h2[1][r]*w3r[1][hh]
                         + h2[2][r]*w3r[2][hh] + h2[3][r]*w3r[3][hh];
        #pragma unroll
        for (int mm = 1; mm < 16; mm <<= 1)
            #pragma unroll
            for (int r = 0; r < 4; ++r)
                #pragma unroll
                for (int hh = 0; hh < 4; ++hh)
                    p[r][hh] += __shfl_xor(p[r][hh], mm, 64);

        if (MODE == 0) {
            if (col < 4) {
                int m = quad*4 + col;
                int e = base + m;
                float o0 = p[0][0], o1 = p[0][1], o2 = p[0][2], o3 = p[0][3];
                if (col == 1) { o0 = p[1][0]; o1 = p[1][1]; o2 = p[1][2]; o3 = p[1][3]; }
                if (col == 2) { o0 = p[2][0]; o1 = p[2][1]; o2 = p[2][2]; o3 = p[2][3]; }
                if (col == 3) { o0 = p[3][0]; o1 = p[3][1]; o2 = p[3][2]; o3 = p[3][3]; }
                float4 o; o.x = o0 + b3r[0]; o.y = o1 + b3r[1]; o.z = o2 + b3r[2]; o.w = o3 + b3r[3];
                *(float4*)(&outbuf[(size_t)e*4]) = o;
            }
        } else {
            int m0  = quad*4 + (col & 3);
            int eaW = __shfl(eaL, m0, 64);
            int ebW = __shfl(ebL, m0, 64);
            int aW  = __shfl(aL,  m0, 64);
            int bW  = __shfl(bL,  m0, 64);
            if (col < 4) {
                float o0 = p[0][0], o1 = p[0][1], o2 = p[0][2], o3 = p[0][3];
                if (col == 1) { o0 = p[1][0]; o1 = p[1][1]; o2 = p[1][2]; o3 = p[1][3]; }
                if (col == 2) { o0 = p[2][0]; o1 = p[2][1]; o2 = p[2][2]; o3 = p[2][3]; }
                if (col == 3) { o0 = p[3][0]; o1 = p[3][1]; o2 = p[3][2]; o3 = p[3][3]; }
                o0 += b3r[0]; o1 += b3r[1]; o2 += b3r[2]; o3 += b3r[3];
                float4 g = *(const float4*)(&a1buf[(size_t)ebW*4]);   // src = eb
                float4 r1; r1.x = o0*g.x; r1.y = o1*g.y; r1.z = o2*g.z; r1.w = o3*g.w;
                *(float4*)(&outbuf[(size_t)(eaW*8 + bW)*4]) = r1;
                if (aW != bW) {
                    float4 g2 = *(const float4*)(&a1buf[(size_t)eaW*4]); // src = ea
                    float4 r2; r2.x = o0*g2.x; r2.y = o1*g2.y; r2.z = o2*g2.z; r2.w = o3*g2.w;
                    *(float4*)(&outbuf[(size_t)(ebW*8 + aW)*4]) = r2;
                }
            }
        }
    }
}

__global__ __launch_bounds__(256, 2) void k_mlp1(
    const float* __restrict__ evec,
    const float* __restrict__ wain, const float* __restrict__ bain,
    const float* __restrict__ ga1p, const float* __restrict__ bea1p,
    const float* __restrict__ wam,  const float* __restrict__ bam,
    const float* __restrict__ ga2p, const float* __restrict__ bea2p,
    const float* __restrict__ wao,  const float* __restrict__ bao,
    float* __restrict__ a1buf)
{
    __shared__ __align__(16) unsigned short hbuf[4096];
    mlp_mfma_body<0>(evec, wain, bain, ga1p, bea1p, wam, bam, ga2p, bea2p,
                     wao, bao, nullptr, a1buf, hbuf);
}

__global__ __launch_bounds__(256, 2) void k_mlp2(
    const float* __restrict__ evec,
    const float* __restrict__ wain, const float* __restrict__ bain,
    const float* __restrict__ ga1p, const float* __restrict__ bea1p,
    const float* __restrict__ wam,  const float* __restrict__ bam,
    const float* __restrict__ ga2p, const float* __restrict__ bea2p,
    const float* __restrict__ wao,  const float* __restrict__ bao,
    const float* __restrict__ a1buf, float* __restrict__ alpha)
{
    __shared__ __align__(16) unsigned short hbuf[4096];
    mlp_mfma_body<1>(evec, wain, bain, ga1p, bea1p, wam, bam, ga2p, bea2p,
                     wao, bao, a1buf, alpha, hbuf);
}

// ---------------------------------------------------------------------------
// Kernel 4: per target edge e: softmax over its 8 triplets (per head), aggregate
// value rows, apply W_lin -> eout[e,0..63] (stored fp16). Wave per edge.
__global__ __launch_bounds__(256) void k_edge(
    const float* __restrict__ alpha, const unsigned short* __restrict__ value,
    const int* __restrict__ src_eid, const int* __restrict__ inv_index,
    const float* __restrict__ wlin, unsigned short* __restrict__ eout)
{
    __shared__ float WL[128*64];
    __shared__ float alsb[4*32];
    __shared__ float feab[4*128];
    const int tid = threadIdx.x;
    for (int i = tid; i < 8192; i += 256) WL[i] = wlin[i];
    __syncthreads();
    const int lane = tid & 63, ws = tid >> 6;
    float* als = alsb + ws * 32;
    float* fea = feab + ws * 128;
    for (int base = blockIdx.x * 4; base < EE; base += gridDim.x * 4) {
        int e = base + ws;
        float v = -1e30f;
        if (lane < 32) v = alpha[(size_t)e*32 + lane];   // lane = b*4+h
        float vm = v;
        vm = fmaxf(vm, __shfl_xor(vm, 4, 64));
        vm = fmaxf(vm, __shfl_xor(vm, 8, 64));
        vm = fmaxf(vm, __shfl_xor(vm, 16, 64));
        float ex = __expf(v - vm);
        float den = ex;
        den += __shfl_xor(den, 4, 64);
        den += __shfl_xor(den, 8, 64);
        den += __shfl_xor(den, 16, 64);
        float al = ex / (den + 1e-16f);
        if (lane < 32) als[lane] = al;
        __syncthreads();
        float f0 = 0.f, f1 = 0.f;
        int h0 = lane >> 5;
        #pragma unroll
        for (int bq = 0; bq < 8; ++bq) {
            int se = src_eid[e*8 + bq];
            int row = inv_index[se];
            const unsigned short* vr = &value[(size_t)row * FF];
            f0 += als[bq*4 + h0]     * h2f(vr[lane]);
            f1 += als[bq*4 + h0 + 2] * h2f(vr[64 + lane]);
        }
        fea[lane] = f0; fea[64 + lane] = f1;
        __syncthreads();
        float acc = 0.f;
        #pragma unroll
        for (int f = 0; f < 128; f += 4) {
            float4 fe = *(const float4*)(&fea[f]);
            acc += fe.x * WL[(f+0)*64 + lane];
            acc += fe.y * WL[(f+1)*64 + lane];
            acc += fe.z * WL[(f+2)*64 + lane];
            acc += fe.w * WL[(f+3)*64 + lane];
        }
        eout[(size_t)e*64 + lane] = f2h(acc);
    }
}

// ---------------------------------------------------------------------------
// Kernel 5: node_out[n,o] = sum_s eout[inv_index[n*8+s], o]; fp32 output.
__global__ __launch_bounds__(256) void k_node(
    const unsigned short* __restrict__ eout, const int* __restrict__ inv_index,
    float* __restrict__ out)
{
    int gid = blockIdx.x * 256 + threadIdx.x;   // exactly N*64 = 512000
    int n = gid >> 6, o = gid & 63;
    float s = 0.f;
    #pragma unroll
    for (int q = 0; q < 8; ++q) {
        int row = inv_index[n*8 + q];
        s += h2f(eout[(size_t)row*64 + o]);
    }
    out[gid] = s;
}

// ---------------------------------------------------------------------------
extern "C" void kernel_launch(void* const* d_in, const int* in_sizes, int n_in,
                              void* d_out, int out_size, void* d_ws, size_t ws_size,
                              hipStream_t stream)
{
    const float* ein  = (const float*)d_in[0];
    const float* esh  = (const float*)d_in[1];
    const float* elem = (const float*)d_in[2];
    const float* evec = (const float*)d_in[3];
    const float* wtp  = (const float*)d_in[4];
    const float* wrad = (const float*)d_in[5];
    const float* wlin = (const float*)d_in[6];
    const float* wain = (const float*)d_in[7];
    const float* bain = (const float*)d_in[8];
    const float* ga1p = (const float*)d_in[9];
    const float* bea1p= (const float*)d_in[10];
    const float* wam  = (const float*)d_in[11];
    const float* bam  = (const float*)d_in[12];
    const float* ga2p = (const float*)d_in[13];
    const float* bea2p= (const float*)d_in[14];
    const float* wao  = (const float*)d_in[15];
    const float* bao  = (const float*)d_in[16];
    const int* inv_index = (const int*)d_in[17];
    const int* src_eid   = (const int*)d_in[19];

    // workspace layout (33.8 MB total), all offsets 16B-aligned
    char* ws = (char*)d_ws;
    unsigned short* value = (unsigned short*)ws;                    // E*128*2 fp16
    float*          a1buf = (float*)(ws + 16384000);                // E*4*4
    float*          alpha = (float*)(ws + 16384000 + 1024000);      // T*4*4
    unsigned short* eoutb = (unsigned short*)(ws + 16384000 + 1024000 + 8192000); // E*64*2 fp16

    hipLaunchKernelGGL(k_value,  dim3(EE/64), dim3(256), 0, stream,
                       ein, esh, elem, wtp, wrad, value);
    hipLaunchKernelGGL(k_mlp1,   dim3(250),  dim3(256), 0, stream,
                       evec, wain, bain, ga1p, bea1p, wam, bam, ga2p, bea2p, wao, bao, a1buf);
    hipLaunchKernelGGL(k_mlp2,   dim3(500),  dim3(256), 0, stream,
                       evec, wain, bain, ga1p, bea1p, wam, bam, ga2p, bea2p, wao, bao,
                       a1buf, alpha);
    hipLaunchKernelGGL(k_edge,   dim3(1024), dim3(256), 0, stream,
                       alpha, value, src_eid, inv_index, wlin, eoutb);
    hipLaunchKernelGGL(k_node,   dim3((NN*CO)/256), dim3(256), 0, stream,
                       eoutb, inv_index, (float*)d_out);
}